// Round 3
// baseline (431.763 us; speedup 1.0000x reference)
//
#include <hip/hip_runtime.h>

// CombinedLoss: 0.7*MSE + 0.3*mean_b softDTW_gamma.  B=64, T=1024, C=8, fp32.
// R10: R9 barrier-free pipeline + per-window latency (W) cuts.
// R7 vs R9 showed W ~= 6.5k cy regardless of sync mechanism -> attack the
// wave-local serial cost: (1) depth-3 uniform column prefetch (load at diag t,
// consume t+2: ~300cy slack >> 120cy LDS latency); (2) interior windows
// capture bottom row in registers, lane63 writes 4x ds_write_b128 per window
// (was 16 per-diag divergent writes); (3) tb+d column index (no serial
// min-chain); (4) v_min3/max3 single-op softmin head; (5) intra-block halo
// prefetch when producer already ahead (steady state: 4 windows ahead).
// Geometry unchanged: 256 blocks x 256 thr, 1 wave/SIMD, waves free-run with
// LDS progress flags; cross-block halo via self-validating 8B atomics.
// ws: [0,256) mse | [256,320) sdtw | u64 rings @ float-offset 320 (~1.6 MB).

constexpr int TT = 1024;
constexpr float ALPHA_ = 0.7f;
constexpr float FINF = 1000000000.0f;
constexpr int RING = 1088;

__device__ __forceinline__ float shflup1(float old0, float v) {
    return __int_as_float(__builtin_amdgcn_update_dpp(
        __float_as_int(old0), __float_as_int(v), 0x138, 0xf, 0xf, false));
}
__device__ __forceinline__ float rotdn1(float v) {
    return __int_as_float(__builtin_amdgcn_update_dpp(
        0, __float_as_int(v), 0x130, 0xf, 0xf, false));
}

__global__ __launch_bounds__(256) void sdtw_band_kernel(
    const float* __restrict__ pred, const float* __restrict__ target,
    float* __restrict__ ws)
{
    __shared__ float4 s_p4[TT * 2];      // col j: [-2t0..3],[-2t4..7]
    __shared__ float  s_y2[TT];
    __shared__ float  s_row[4][1088];    // per-wave bottom row, full length
    __shared__ float  s_scr[84];         // scratch sink (edge-window writes)
    __shared__ float  s_red[4];
    __shared__ int    s_prog[4];         // last completed abs window per wave

    const int blk = blockIdx.x;
    const int b   = blk & 63;                  // batch (q*64+b: same-XCD bands)
    const int q   = blk >> 6;                  // band
    const int tid = threadIdx.x;
    const int l   = tid & 63;
    const int w_  = __builtin_amdgcn_readfirstlane(tid >> 6);
    const int g   = (q << 2) + w_;             // global wave 0..15
    const int gbase = g << 6;
    const int row   = gbase + l;

    if (tid < 4) s_prog[tid] = -1;

    const float* pr = pred   + ((size_t)b * TT + row) * 8;
    const float* tr = target + ((size_t)b * TT + row) * 8;
    const float4 pa = ((const float4*)pr)[0];
    const float4 pb = ((const float4*)pr)[1];
    const float4 ma = ((const float4*)tr)[0];
    const float4 mb = ((const float4*)tr)[1];

    float x2 = 0.f, msep = 0.f;
    {
        const float pp[8] = {pa.x,pa.y,pa.z,pa.w,pb.x,pb.y,pb.z,pb.w};
        const float tt[8] = {ma.x,ma.y,ma.z,ma.w,mb.x,mb.y,mb.z,mb.w};
        #pragma unroll
        for (int c = 0; c < 8; ++c) {
            x2 = fmaf(pp[c], pp[c], x2);
            float d = pp[c] - tt[c];
            msep = fmaf(d, d, msep);
        }
    }
    // stage all 1024 columns (4 per thread)
    const float* tg = target + (size_t)b * TT * 8;
    #pragma unroll
    for (int c0 = 0; c0 < 4; ++c0) {
        const int col = tid + (c0 << 8);
        const float4 u0 = ((const float4*)(tg + (size_t)col * 8))[0];
        const float4 u1 = ((const float4*)(tg + (size_t)col * 8))[1];
        s_p4[2*col]   = make_float4(-2.f*u0.x, -2.f*u0.y, -2.f*u0.z, -2.f*u0.w);
        s_p4[2*col+1] = make_float4(-2.f*u1.x, -2.f*u1.y, -2.f*u1.z, -2.f*u1.w);
        s_y2[col] = u0.x*u0.x + u0.y*u0.y + u0.z*u0.z + u0.w*u0.w
                  + u1.x*u1.x + u1.y*u1.y + u1.z*u1.z + u1.w*u1.w;
    }
    #pragma unroll
    for (int off = 32; off > 0; off >>= 1) msep += __shfl_down(msep, off, 64);
    if (l == 0) s_red[w_] = msep;
    __syncthreads();                      // the ONLY block-wide barrier
    if (tid == 0) ws[blk] = s_red[0] + s_red[1] + s_red[2] + s_red[3];

    unsigned long long* rings = (unsigned long long*)(ws + 320);
    unsigned long long* pub = rings + (size_t)(q * 64 + b) * RING;       // w_==3,q<3
    unsigned long long* con = rings + (size_t)((q - 1) * 64 + b) * RING; // w_==0,q>0
    const int kb_pub   = 256 * q + 192;
    const int kb_con   = 256 * q - 64;
    const int kmax_con = kb_con + 1086;

    const float c1 = 7.213475204444817f;     // log2(e)/gamma
    const float c2 = 0.13862943611198906f;   // gamma*ln(2)
    const int amin = g << 2;                 // first abs window = 4g
    const int amax = amin + 67;
    const int prodmax = amin + 63;           // producer wave's amax = 4(g-1)+67

    float r1 = FINF, r2 = FINF;
    float tf0=0,tf1=0,tf2=0,tf3=0,tf4=0,tf5=0,tf6=0,tf7=0, y2f=0;
    // depth-3 uniform column pipeline: A0/B0/ya = col tb, A1=tb+1, A2=tb+2
    float4 A0 = s_p4[0], B0 = s_p4[1];
    float4 A1 = s_p4[2], B1 = s_p4[3];
    float4 A2 = s_p4[4], B2 = s_p4[5];
    float  ya = s_y2[0], yb = s_y2[1], yc = s_y2[2];
    int tb = 0;                              // diag calls completed (col of A0)
    unsigned long long pe1 = 0, pe2 = 0;
    int ppf = 0;
    float hpf1 = 0.f, hpf2 = 0.f;
    int hpff = 0;

    for (int a = amin; a <= amax; ++a) {
        const int k0 = a << 4;
        const int u  = a - amin;                 // 0..67
        const int ndv = (u == 67) ? 14 : 15;     // last diag offset

        // ---- stage halo hv (diag k-1) / hvd (diag k-2), row gbase-1 ----
        float hv, hvd;
        if (w_ == 0) {
            if (q == 0) {
                hv  = FINF;
                hvd = (u == 0 && l == 0) ? 0.0f : FINF;
            } else {
                const int kk1 = k0 - 1 + l, kk2 = k0 - 2 + l;
                const int id1 = min(kk1 - kb_con, RING - 1);
                const int id2 = min(kk2 - kb_con, RING - 1);
                const bool n1 = (l < 16) && (kk1 <= kmax_con);
                const bool n2 = (l < 16) && (kk2 <= kmax_con);
                unsigned long long e1, e2;
                if (ppf) { e1 = pe1; e2 = pe2; ppf = 0; }
                else {
                    e1 = __hip_atomic_load(con + id1, __ATOMIC_RELAXED,
                                           __HIP_MEMORY_SCOPE_AGENT);
                    e2 = __hip_atomic_load(con + id2, __ATOMIC_RELAXED,
                                           __HIP_MEMORY_SCOPE_AGENT);
                }
                while (!__all(((!n1) | ((int)(e1 >> 32) == kk1)) &
                              ((!n2) | ((int)(e2 >> 32) == kk2)))) {
                    e1 = __hip_atomic_load(con + id1, __ATOMIC_RELAXED,
                                           __HIP_MEMORY_SCOPE_AGENT);
                    e2 = __hip_atomic_load(con + id2, __ATOMIC_RELAXED,
                                           __HIP_MEMORY_SCOPE_AGENT);
                }
                hv  = n1 ? __uint_as_float((unsigned)e1) : FINF;
                hvd = n2 ? __uint_as_float((unsigned)e2) : FINF;
            }
        } else {
            if (hpff) { hv = hpf1; hvd = hpf2; hpff = 0; }
            else {
                const int need = (a < prodmax) ? a : prodmax;
                int pv;
                do {
                    pv = __hip_atomic_load(&s_prog[w_ - 1], __ATOMIC_ACQUIRE,
                                           __HIP_MEMORY_SCOPE_WORKGROUP);
                } while (pv < need);
                const int bi = (u << 4) + 63 + l;     // k0-1+l in producer row
                hv  = s_row[w_ - 1][min(bi,     1087)];
                hvd = s_row[w_ - 1][min(bi - 1, 1087)];
            }
        }
        float* wrp = (l == 63) ? &s_row[w_][u << 4] : &s_scr[l];

        auto diag = [&](int d, bool edge_, bool store_) {
            tf0 = shflup1(A0.x, tf0); tf1 = shflup1(A0.y, tf1);
            tf2 = shflup1(A0.z, tf2); tf3 = shflup1(A0.w, tf3);
            tf4 = shflup1(B0.x, tf4); tf5 = shflup1(B0.y, tf5);
            tf6 = shflup1(B0.z, tf6); tf7 = shflup1(B0.w, tf7);
            y2f = shflup1(ya, y2f);
            const float up   = shflup1(hv,  r1);
            const float dg   = shflup1(hvd, r2);
            const float left = r1;
            hv = rotdn1(hv); hvd = rotdn1(hvd);
            A0 = A1; B0 = B1; ya = yb;
            A1 = A2; B1 = B2; yb = yc;
            const int cc = tb + d + 3;
            const int jn = (cc < TT) ? cc : (TT - 1);
            A2 = s_p4[2*jn]; B2 = s_p4[2*jn + 1]; yc = s_y2[jn];
            float acc  = x2 + y2f;
            float acc2 = 0.f;
            acc  = fmaf(pa.x, tf0, acc);  acc2 = fmaf(pa.y, tf1, acc2);
            acc  = fmaf(pa.z, tf2, acc);  acc2 = fmaf(pa.w, tf3, acc2);
            acc  = fmaf(pb.x, tf4, acc);  acc2 = fmaf(pb.y, tf5, acc2);
            acc  = fmaf(pb.z, tf6, acc);  acc2 = fmaf(pb.w, tf7, acc2);
            acc += acc2;
            float m, M;
            asm("v_min3_f32 %0, %1, %2, %3" : "=v"(m) : "v"(up), "v"(left), "v"(dg));
            asm("v_max3_f32 %0, %1, %2, %3" : "=v"(M) : "v"(up), "v"(left), "v"(dg));
            const float md = __builtin_amdgcn_fmed3f(up, left, dg);
            const float mc = m * c1;
            const float e1 = __builtin_amdgcn_exp2f(fmaf(md, -c1, mc));
            const float e2 = __builtin_amdgcn_exp2f(fmaf(M,  -c1, mc));
            const float lg = __builtin_amdgcn_logf(1.0f + (e1 + e2));
            float rn = acc + fmaf(-c2, lg, m);
            if (edge_) {
                const int jj = k0 + d - row;
                rn = ((unsigned)jj < (unsigned)TT) ? rn : FINF;
            }
            r2 = r1; r1 = rn;
            if (store_) wrp[d] = rn;
        };

        if (u >= 4 && u <= 63) {
            float rh0,rh1,rh2,rh3,rh4,rh5,rh6,rh7;
            float rh8,rh9,rh10,rh11,rh12,rh13,rh14,rh15;
            diag( 0,false,false); rh0 =r1; diag( 1,false,false); rh1 =r1;
            diag( 2,false,false); rh2 =r1; diag( 3,false,false); rh3 =r1;
            diag( 4,false,false); rh4 =r1; diag( 5,false,false); rh5 =r1;
            diag( 6,false,false); rh6 =r1; diag( 7,false,false); rh7 =r1;
            diag( 8,false,false); rh8 =r1; diag( 9,false,false); rh9 =r1;
            diag(10,false,false); rh10=r1; diag(11,false,false); rh11=r1;
            diag(12,false,false); rh12=r1; diag(13,false,false); rh13=r1;
            diag(14,false,false); rh14=r1; diag(15,false,false); rh15=r1;
            if (l == 63) {
                float4* dst = (float4*)&s_row[w_][u << 4];
                dst[0] = make_float4(rh0, rh1, rh2, rh3);
                dst[1] = make_float4(rh4, rh5, rh6, rh7);
                dst[2] = make_float4(rh8, rh9, rh10, rh11);
                dst[3] = make_float4(rh12, rh13, rh14, rh15);
            }
            tb += 16;
        } else {
            for (int d = 0; d <= ndv; ++d) diag(d, true, true);
            tb += ndv + 1;
        }

        // ---- mark window complete for intra-block consumer (ASAP) ----
        if (w_ < 3 && l == 0) {
            __hip_atomic_store(&s_prog[w_], a, __ATOMIC_RELEASE,
                               __HIP_MEMORY_SCOPE_WORKGROUP);
        }
        // ---- producer: publish window as self-validating u64 entries ----
        if (w_ == 3 && q < 3) {
            if (l <= ndv) {
                const int kk = k0 + l;
                const unsigned long long ev =
                    ((unsigned long long)(unsigned)kk << 32) |
                    (unsigned long long)__float_as_uint(s_row[3][(u << 4) + l]);
                __hip_atomic_store(pub + (kk - kb_pub), ev,
                                   __ATOMIC_RELAXED, __HIP_MEMORY_SCOPE_AGENT);
            }
        }
        // ---- cross-block consumer: prefetch next window's halo entries ----
        if (w_ == 0 && q > 0 && a < amax) {
            const int k0n = k0 + 16;
            const int kk1 = k0n - 1 + l, kk2 = k0n - 2 + l;
            pe1 = __hip_atomic_load(con + min(kk1 - kb_con, RING - 1),
                                    __ATOMIC_RELAXED, __HIP_MEMORY_SCOPE_AGENT);
            pe2 = __hip_atomic_load(con + min(kk2 - kb_con, RING - 1),
                                    __ATOMIC_RELAXED, __HIP_MEMORY_SCOPE_AGENT);
            ppf = 1;
        }
        // ---- intra-block consumer: prefetch next window's halo if ready ----
        if (w_ != 0 && a < amax) {
            const int neednx = ((a + 1) < prodmax) ? (a + 1) : prodmax;
            const int pv = __hip_atomic_load(&s_prog[w_ - 1], __ATOMIC_ACQUIRE,
                                             __HIP_MEMORY_SCOPE_WORKGROUP);
            if (pv >= neednx) {
                const int bi = ((u + 1) << 4) + 63 + l;
                hpf1 = s_row[w_ - 1][min(bi,     1087)];
                hpf2 = s_row[w_ - 1][min(bi - 1, 1087)];
                hpff = 1;
            }
        }
    }
    if (q == 3 && tid == 255) ws[256 + b] = r1;      // r_{2T-2}(T-1)
}

__global__ __launch_bounds__(256) void finalize2_kernel(
    const float* __restrict__ ws, float* __restrict__ out)
{
    __shared__ float sm[4], ss[4];
    const int tid = threadIdx.x, l = tid & 63, w = tid >> 6;
    float m  = ws[tid];
    float sd = (tid < 64) ? ws[256 + tid] : 0.f;
    #pragma unroll
    for (int off = 32; off > 0; off >>= 1) {
        m  += __shfl_down(m,  off, 64);
        sd += __shfl_down(sd, off, 64);
    }
    if (l == 0) { sm[w] = m; ss[w] = sd; }
    __syncthreads();
    if (tid == 0) {
        float M = sm[0] + sm[1] + sm[2] + sm[3];
        float S = ss[0] + ss[1] + ss[2] + ss[3];
        out[0] = ALPHA_ * (M / 524288.0f) + (1.0f - ALPHA_) * (S / 64.0f);
    }
}

extern "C" void kernel_launch(void* const* d_in, const int* in_sizes, int n_in,
                              void* d_out, int out_size, void* d_ws, size_t ws_size,
                              hipStream_t stream) {
    const float* pred   = (const float*)d_in[0];
    const float* target = (const float*)d_in[1];
    float* ws  = (float*)d_ws;
    float* out = (float*)d_out;

    sdtw_band_kernel<<<256, 256, 0, stream>>>(pred, target, ws);
    finalize2_kernel<<<1, 256, 0, stream>>>(ws, out);
}

// Round 4
// 427.509 us; speedup vs baseline: 1.0099x; 1.0099x over previous
//
#include <hip/hip_runtime.h>

// CombinedLoss: 0.7*MSE + 0.3*mean_b softDTW_gamma.  B=64, T=1024, C=8, fp32.
// R11: two-phase windows. R9/R10 exonerated sync, LDS latency, bank conflicts;
// per-diag cost stuck at ~400cy with ~100cy issue -> in-order chain exposure.
// Interior windows now: D-phase (16 distance values via tf-DPP pipeline, pure
// ILP, no recurrence dependence) then R-phase (pure softmin recurrence,
// ~15 insts/step, only the irreducible chain). Halo staging sits between the
// phases so producer-spin overlaps D-work. Edge windows keep interleaved path.
// Geometry unchanged: 256 blocks x 256 thr, 1 wave/SIMD, free-running waves,
// LDS progress flags intra-block, self-validating 8B atomics cross-block.
// ws: [0,256) mse | [256,320) sdtw | u64 rings @ float-offset 320 (~1.6 MB).

constexpr int TT = 1024;
constexpr float ALPHA_ = 0.7f;
constexpr float FINF = 1000000000.0f;
constexpr int RING = 1088;

__device__ __forceinline__ float shflup1(float old0, float v) {
    return __int_as_float(__builtin_amdgcn_update_dpp(
        __float_as_int(old0), __float_as_int(v), 0x138, 0xf, 0xf, false));
}
__device__ __forceinline__ float rotdn1(float v) {
    return __int_as_float(__builtin_amdgcn_update_dpp(
        0, __float_as_int(v), 0x130, 0xf, 0xf, false));
}

__global__ __launch_bounds__(256) void sdtw_band_kernel(
    const float* __restrict__ pred, const float* __restrict__ target,
    float* __restrict__ ws)
{
    __shared__ float4 s_p4[TT * 2];      // col j: [-2t0..3],[-2t4..7]
    __shared__ float  s_y2[TT];
    __shared__ float  s_row[4][1088];    // per-wave bottom row, full length
    __shared__ float  s_scr[84];         // scratch sink (edge-window writes)
    __shared__ float  s_red[4];
    __shared__ int    s_prog[4];         // last completed abs window per wave

    const int blk = blockIdx.x;
    const int b   = blk & 63;                  // batch (q*64+b: same-XCD bands)
    const int q   = blk >> 6;                  // band
    const int tid = threadIdx.x;
    const int l   = tid & 63;
    const int w_  = __builtin_amdgcn_readfirstlane(tid >> 6);
    const int g   = (q << 2) + w_;             // global wave 0..15
    const int gbase = g << 6;
    const int row   = gbase + l;

    if (tid < 4) s_prog[tid] = -1;

    const float* pr = pred   + ((size_t)b * TT + row) * 8;
    const float* tr = target + ((size_t)b * TT + row) * 8;
    const float4 pa = ((const float4*)pr)[0];
    const float4 pb = ((const float4*)pr)[1];
    const float4 ma = ((const float4*)tr)[0];
    const float4 mb = ((const float4*)tr)[1];

    float x2 = 0.f, msep = 0.f;
    {
        const float pp[8] = {pa.x,pa.y,pa.z,pa.w,pb.x,pb.y,pb.z,pb.w};
        const float tt[8] = {ma.x,ma.y,ma.z,ma.w,mb.x,mb.y,mb.z,mb.w};
        #pragma unroll
        for (int c = 0; c < 8; ++c) {
            x2 = fmaf(pp[c], pp[c], x2);
            float d = pp[c] - tt[c];
            msep = fmaf(d, d, msep);
        }
    }
    // stage all 1024 columns (4 per thread)
    const float* tg = target + (size_t)b * TT * 8;
    #pragma unroll
    for (int c0 = 0; c0 < 4; ++c0) {
        const int col = tid + (c0 << 8);
        const float4 u0 = ((const float4*)(tg + (size_t)col * 8))[0];
        const float4 u1 = ((const float4*)(tg + (size_t)col * 8))[1];
        s_p4[2*col]   = make_float4(-2.f*u0.x, -2.f*u0.y, -2.f*u0.z, -2.f*u0.w);
        s_p4[2*col+1] = make_float4(-2.f*u1.x, -2.f*u1.y, -2.f*u1.z, -2.f*u1.w);
        s_y2[col] = u0.x*u0.x + u0.y*u0.y + u0.z*u0.z + u0.w*u0.w
                  + u1.x*u1.x + u1.y*u1.y + u1.z*u1.z + u1.w*u1.w;
    }
    #pragma unroll
    for (int off = 32; off > 0; off >>= 1) msep += __shfl_down(msep, off, 64);
    if (l == 0) s_red[w_] = msep;
    __syncthreads();                      // the ONLY block-wide barrier
    if (tid == 0) ws[blk] = s_red[0] + s_red[1] + s_red[2] + s_red[3];

    unsigned long long* rings = (unsigned long long*)(ws + 320);
    unsigned long long* pub = rings + (size_t)(q * 64 + b) * RING;       // w_==3,q<3
    unsigned long long* con = rings + (size_t)((q - 1) * 64 + b) * RING; // w_==0,q>0
    const int kb_pub   = 256 * q + 192;
    const int kb_con   = 256 * q - 64;
    const int kmax_con = kb_con + 1086;

    const float c1 = 7.213475204444817f;     // log2(e)/gamma
    const float c2 = 0.13862943611198906f;   // gamma*ln(2)
    const int amin = g << 2;                 // first abs window = 4g
    const int amax = amin + 67;
    const int prodmax = amin + 63;           // producer wave's amax = 4(g-1)+67

    float r1 = FINF, r2 = FINF;
    float tf0=0,tf1=0,tf2=0,tf3=0,tf4=0,tf5=0,tf6=0,tf7=0, y2f=0;
    // depth-3 uniform column pipeline: A0/B0/ya = col tb, A1=tb+1, A2=tb+2
    float4 A0 = s_p4[0], B0 = s_p4[1];
    float4 A1 = s_p4[2], B1 = s_p4[3];
    float4 A2 = s_p4[4], B2 = s_p4[5];
    float  ya = s_y2[0], yb = s_y2[1], yc = s_y2[2];
    int tb = 0;                              // diag calls completed (col of A0)
    unsigned long long pe1 = 0, pe2 = 0;
    int ppf = 0;
    float hpf1 = 0.f, hpf2 = 0.f;
    int hpff = 0;
    float hv, hvd;

    // stage halo hv (diag k0-1) / hvd (diag k0-2), row gbase-1
    auto stage_halo = [&](int a, int k0, int u) {
        if (w_ == 0) {
            if (q == 0) {
                hv  = FINF;
                hvd = (u == 0 && l == 0) ? 0.0f : FINF;
            } else {
                const int kk1 = k0 - 1 + l, kk2 = k0 - 2 + l;
                const int id1 = min(kk1 - kb_con, RING - 1);
                const int id2 = min(kk2 - kb_con, RING - 1);
                const bool n1 = (l < 16) && (kk1 <= kmax_con);
                const bool n2 = (l < 16) && (kk2 <= kmax_con);
                unsigned long long e1, e2;
                if (ppf) { e1 = pe1; e2 = pe2; ppf = 0; }
                else {
                    e1 = __hip_atomic_load(con + id1, __ATOMIC_RELAXED,
                                           __HIP_MEMORY_SCOPE_AGENT);
                    e2 = __hip_atomic_load(con + id2, __ATOMIC_RELAXED,
                                           __HIP_MEMORY_SCOPE_AGENT);
                }
                while (!__all(((!n1) | ((int)(e1 >> 32) == kk1)) &
                              ((!n2) | ((int)(e2 >> 32) == kk2)))) {
                    e1 = __hip_atomic_load(con + id1, __ATOMIC_RELAXED,
                                           __HIP_MEMORY_SCOPE_AGENT);
                    e2 = __hip_atomic_load(con + id2, __ATOMIC_RELAXED,
                                           __HIP_MEMORY_SCOPE_AGENT);
                }
                hv  = n1 ? __uint_as_float((unsigned)e1) : FINF;
                hvd = n2 ? __uint_as_float((unsigned)e2) : FINF;
            }
        } else {
            if (hpff) { hv = hpf1; hvd = hpf2; hpff = 0; }
            else {
                const int need = (a < prodmax) ? a : prodmax;
                int pv;
                do {
                    pv = __hip_atomic_load(&s_prog[w_ - 1], __ATOMIC_ACQUIRE,
                                           __HIP_MEMORY_SCOPE_WORKGROUP);
                } while (pv < need);
                const int bi = (u << 4) + 63 + l;     // k0-1+l in producer row
                hv  = s_row[w_ - 1][min(bi,     1087)];
                hvd = s_row[w_ - 1][min(bi - 1, 1087)];
            }
        }
    };

// D-phase step: advance tf/column pipeline, produce one distance value
#define DSTEP(d, DV) do {                                                   \
        tf0 = shflup1(A0.x, tf0); tf1 = shflup1(A0.y, tf1);                 \
        tf2 = shflup1(A0.z, tf2); tf3 = shflup1(A0.w, tf3);                 \
        tf4 = shflup1(B0.x, tf4); tf5 = shflup1(B0.y, tf5);                 \
        tf6 = shflup1(B0.z, tf6); tf7 = shflup1(B0.w, tf7);                 \
        y2f = shflup1(ya, y2f);                                             \
        A0 = A1; B0 = B1; ya = yb;                                          \
        A1 = A2; B1 = B2; yb = yc;                                          \
        const int cc = tb + (d) + 3;                                        \
        const int jn = (cc < TT) ? cc : (TT - 1);                           \
        A2 = s_p4[2*jn]; B2 = s_p4[2*jn + 1]; yc = s_y2[jn];                \
        float acc = x2 + y2f, acc2 = 0.f;                                   \
        acc  = fmaf(pa.x, tf0, acc);  acc2 = fmaf(pa.y, tf1, acc2);         \
        acc  = fmaf(pa.z, tf2, acc);  acc2 = fmaf(pa.w, tf3, acc2);         \
        acc  = fmaf(pb.x, tf4, acc);  acc2 = fmaf(pb.y, tf5, acc2);         \
        acc  = fmaf(pb.z, tf6, acc);  acc2 = fmaf(pb.w, tf7, acc2);         \
        DV = acc + acc2;                                                    \
    } while (0)

// R-phase step: pure recurrence, distance comes in pre-computed
#define RSTEP(DV, RH) do {                                                  \
        const float up   = shflup1(hv,  r1);                                \
        const float dg   = shflup1(hvd, r2);                                \
        const float left = r1;                                              \
        hv = rotdn1(hv); hvd = rotdn1(hvd);                                 \
        float m_, M_;                                                       \
        asm("v_min3_f32 %0, %1, %2, %3"                                     \
            : "=v"(m_) : "v"(up), "v"(left), "v"(dg));                      \
        asm("v_max3_f32 %0, %1, %2, %3"                                     \
            : "=v"(M_) : "v"(up), "v"(left), "v"(dg));                      \
        const float md_ = __builtin_amdgcn_fmed3f(up, left, dg);            \
        const float mc_ = m_ * c1;                                          \
        const float ea_ = __builtin_amdgcn_exp2f(fmaf(md_, -c1, mc_));      \
        const float eb_ = __builtin_amdgcn_exp2f(fmaf(M_,  -c1, mc_));      \
        const float lg_ = __builtin_amdgcn_logf(1.0f + (ea_ + eb_));        \
        const float rn_ = DV + fmaf(-c2, lg_, m_);                          \
        r2 = r1; r1 = rn_; RH = rn_;                                        \
    } while (0)

    // interleaved edge-window step (original path)
    auto diag = [&](int k0, int d) {
        float Dv;
        DSTEP(d, Dv);
        const float up   = shflup1(hv,  r1);
        const float dg   = shflup1(hvd, r2);
        const float left = r1;
        hv = rotdn1(hv); hvd = rotdn1(hvd);
        float m_, M_;
        asm("v_min3_f32 %0, %1, %2, %3" : "=v"(m_) : "v"(up), "v"(left), "v"(dg));
        asm("v_max3_f32 %0, %1, %2, %3" : "=v"(M_) : "v"(up), "v"(left), "v"(dg));
        const float md_ = __builtin_amdgcn_fmed3f(up, left, dg);
        const float mc_ = m_ * c1;
        const float ea_ = __builtin_amdgcn_exp2f(fmaf(md_, -c1, mc_));
        const float eb_ = __builtin_amdgcn_exp2f(fmaf(M_,  -c1, mc_));
        const float lg_ = __builtin_amdgcn_logf(1.0f + (ea_ + eb_));
        float rn = Dv + fmaf(-c2, lg_, m_);
        const int jj = k0 + d - row;
        rn = ((unsigned)jj < (unsigned)TT) ? rn : FINF;
        r2 = r1; r1 = rn;
        float* wrp = (l == 63) ? &s_row[w_][(k0 >> 4 << 4) - (amin << 4) + d]
                               : &s_scr[l];
        // note: k0 is window-aligned so (k0>>4<<4) == k0; index = u*16 + d
        wrp[0] = rn;
    };

    for (int a = amin; a <= amax; ++a) {
        const int k0 = a << 4;
        const int u  = a - amin;                 // 0..67
        const int ndv = (u == 67) ? 14 : 15;     // last diag offset

        if (u >= 4 && u <= 63) {
            // ---- D-phase: 16 distance values, pure ILP ----
            float D0,D1,D2,D3,D4,D5,D6,D7,D8,D9,D10,D11,D12,D13,D14,D15;
            DSTEP( 0,D0 ); DSTEP( 1,D1 ); DSTEP( 2,D2 ); DSTEP( 3,D3 );
            DSTEP( 4,D4 ); DSTEP( 5,D5 ); DSTEP( 6,D6 ); DSTEP( 7,D7 );
            DSTEP( 8,D8 ); DSTEP( 9,D9 ); DSTEP(10,D10); DSTEP(11,D11);
            DSTEP(12,D12); DSTEP(13,D13); DSTEP(14,D14); DSTEP(15,D15);
            tb += 16;
            // ---- halo staging between phases (spin overlaps D-work) ----
            stage_halo(a, k0, u);
            // ---- R-phase: pure recurrence ----
            float rh0,rh1,rh2,rh3,rh4,rh5,rh6,rh7;
            float rh8,rh9,rh10,rh11,rh12,rh13,rh14,rh15;
            RSTEP(D0 ,rh0 ); RSTEP(D1 ,rh1 ); RSTEP(D2 ,rh2 ); RSTEP(D3 ,rh3 );
            RSTEP(D4 ,rh4 ); RSTEP(D5 ,rh5 ); RSTEP(D6 ,rh6 ); RSTEP(D7 ,rh7 );
            RSTEP(D8 ,rh8 ); RSTEP(D9 ,rh9 ); RSTEP(D10,rh10); RSTEP(D11,rh11);
            RSTEP(D12,rh12); RSTEP(D13,rh13); RSTEP(D14,rh14); RSTEP(D15,rh15);
            if (l == 63) {
                float4* dst = (float4*)&s_row[w_][u << 4];
                dst[0] = make_float4(rh0, rh1, rh2, rh3);
                dst[1] = make_float4(rh4, rh5, rh6, rh7);
                dst[2] = make_float4(rh8, rh9, rh10, rh11);
                dst[3] = make_float4(rh12, rh13, rh14, rh15);
            }
        } else {
            stage_halo(a, k0, u);
            for (int d = 0; d <= ndv; ++d) diag(k0, d);
            tb += ndv + 1;
        }

        // ---- mark window complete for intra-block consumer (ASAP) ----
        if (w_ < 3 && l == 0) {
            __hip_atomic_store(&s_prog[w_], a, __ATOMIC_RELEASE,
                               __HIP_MEMORY_SCOPE_WORKGROUP);
        }
        // ---- producer: publish window as self-validating u64 entries ----
        if (w_ == 3 && q < 3) {
            if (l <= ndv) {
                const int kk = k0 + l;
                const unsigned long long ev =
                    ((unsigned long long)(unsigned)kk << 32) |
                    (unsigned long long)__float_as_uint(s_row[3][(u << 4) + l]);
                __hip_atomic_store(pub + (kk - kb_pub), ev,
                                   __ATOMIC_RELAXED, __HIP_MEMORY_SCOPE_AGENT);
            }
        }
        // ---- cross-block consumer: prefetch next window's halo entries ----
        if (w_ == 0 && q > 0 && a < amax) {
            const int k0n = k0 + 16;
            const int kk1 = k0n - 1 + l, kk2 = k0n - 2 + l;
            pe1 = __hip_atomic_load(con + min(kk1 - kb_con, RING - 1),
                                    __ATOMIC_RELAXED, __HIP_MEMORY_SCOPE_AGENT);
            pe2 = __hip_atomic_load(con + min(kk2 - kb_con, RING - 1),
                                    __ATOMIC_RELAXED, __HIP_MEMORY_SCOPE_AGENT);
            ppf = 1;
        }
        // ---- intra-block consumer: prefetch next window's halo if ready ----
        if (w_ != 0 && a < amax) {
            const int neednx = ((a + 1) < prodmax) ? (a + 1) : prodmax;
            const int pv = __hip_atomic_load(&s_prog[w_ - 1], __ATOMIC_ACQUIRE,
                                             __HIP_MEMORY_SCOPE_WORKGROUP);
            if (pv >= neednx) {
                const int bi = ((u + 1) << 4) + 63 + l;
                hpf1 = s_row[w_ - 1][min(bi,     1087)];
                hpf2 = s_row[w_ - 1][min(bi - 1, 1087)];
                hpff = 1;
            }
        }
    }
    if (q == 3 && tid == 255) ws[256 + b] = r1;      // r_{2T-2}(T-1)
#undef DSTEP
#undef RSTEP
}

__global__ __launch_bounds__(256) void finalize2_kernel(
    const float* __restrict__ ws, float* __restrict__ out)
{
    __shared__ float sm[4], ss[4];
    const int tid = threadIdx.x, l = tid & 63, w = tid >> 6;
    float m  = ws[tid];
    float sd = (tid < 64) ? ws[256 + tid] : 0.f;
    #pragma unroll
    for (int off = 32; off > 0; off >>= 1) {
        m  += __shfl_down(m,  off, 64);
        sd += __shfl_down(sd, off, 64);
    }
    if (l == 0) { sm[w] = m; ss[w] = sd; }
    __syncthreads();
    if (tid == 0) {
        float M = sm[0] + sm[1] + sm[2] + sm[3];
        float S = ss[0] + ss[1] + ss[2] + ss[3];
        out[0] = ALPHA_ * (M / 524288.0f) + (1.0f - ALPHA_) * (S / 64.0f);
    }
}

extern "C" void kernel_launch(void* const* d_in, const int* in_sizes, int n_in,
                              void* d_out, int out_size, void* d_ws, size_t ws_size,
                              hipStream_t stream) {
    const float* pred   = (const float*)d_in[0];
    const float* target = (const float*)d_in[1];
    float* ws  = (float*)d_ws;
    float* out = (float*)d_out;

    sdtw_band_kernel<<<256, 256, 0, stream>>>(pred, target, ws);
    finalize2_kernel<<<1, 256, 0, stream>>>(ws, out);
}

// Round 6
// 313.986 us; speedup vs baseline: 1.3751x; 1.3616x over previous
//
#include <hip/hip_runtime.h>

// CombinedLoss: 0.7*MSE + 0.3*mean_b softDTW_gamma.  B=64, T=1024, C=8, fp32.
// R13 (= R12 resubmit; round-5 bench died at container acquire, audit found
// no hang/OOB path): direct per-lane D loads + fused R(u)||D(u+1) windows.
// R10 proved bank conflicts are free -> drop the DPP column-streaming pipeline
// (9 DPP + 18 mov per diag, serial across diags). Lane l reads column
// j = 16u+d-l straight from LDS (2x ds_read_b128 + ds_read_b32 + 8 FMA, all
// 16 diags independent). Each window fuses the serial softmin recurrence of
// window u with the independent D-computation of window u+1 in ONE straight-
// line block, so every ~70-120cy R-chain step has ~13 independent insts + LDS
// loads to hide under it.  Geometry/sync unchanged from R9: 256 blocks x 256
// thr, 1 wave/SIMD, free-running waves, LDS progress flags intra-block,
// self-validating 8B atomics cross-block.
// ws: [0,256) mse | [256,320) sdtw | u64 rings @ float-offset 320 (~1.6 MB).

constexpr int TT = 1024;
constexpr float ALPHA_ = 0.7f;
constexpr float FINF = 1000000000.0f;
constexpr int RING = 1088;

__device__ __forceinline__ float shflup1(float old0, float v) {
    return __int_as_float(__builtin_amdgcn_update_dpp(
        __float_as_int(old0), __float_as_int(v), 0x138, 0xf, 0xf, false));
}
__device__ __forceinline__ float rotdn1(float v) {
    return __int_as_float(__builtin_amdgcn_update_dpp(
        0, __float_as_int(v), 0x130, 0xf, 0xf, false));
}

__global__ __launch_bounds__(256) void sdtw_band_kernel(
    const float* __restrict__ pred, const float* __restrict__ target,
    float* __restrict__ ws)
{
    __shared__ float4 s_p4[TT * 2];      // col j: [-2t0..3],[-2t4..7]
    __shared__ float  s_y2[TT];
    __shared__ float  s_row[4][1088];    // per-wave bottom row, full length
    __shared__ float  s_red[4];
    __shared__ int    s_prog[4];         // last completed abs window per wave

    const int blk = blockIdx.x;
    const int b   = blk & 63;                  // batch (q*64+b: same-XCD bands)
    const int q   = blk >> 6;                  // band
    const int tid = threadIdx.x;
    const int l   = tid & 63;
    const int w_  = __builtin_amdgcn_readfirstlane(tid >> 6);
    const int g   = (q << 2) + w_;             // global wave 0..15
    const int gbase = g << 6;
    const int row   = gbase + l;

    if (tid < 4) s_prog[tid] = -1;

    const float* pr = pred   + ((size_t)b * TT + row) * 8;
    const float* tr = target + ((size_t)b * TT + row) * 8;
    const float4 pa = ((const float4*)pr)[0];
    const float4 pb = ((const float4*)pr)[1];
    const float4 ma = ((const float4*)tr)[0];
    const float4 mb = ((const float4*)tr)[1];

    float x2 = 0.f, msep = 0.f;
    {
        const float pp[8] = {pa.x,pa.y,pa.z,pa.w,pb.x,pb.y,pb.z,pb.w};
        const float tt[8] = {ma.x,ma.y,ma.z,ma.w,mb.x,mb.y,mb.z,mb.w};
        #pragma unroll
        for (int c = 0; c < 8; ++c) {
            x2 = fmaf(pp[c], pp[c], x2);
            float d = pp[c] - tt[c];
            msep = fmaf(d, d, msep);
        }
    }
    // stage all 1024 columns (4 per thread)
    const float* tg = target + (size_t)b * TT * 8;
    #pragma unroll
    for (int c0 = 0; c0 < 4; ++c0) {
        const int col = tid + (c0 << 8);
        const float4 u0 = ((const float4*)(tg + (size_t)col * 8))[0];
        const float4 u1 = ((const float4*)(tg + (size_t)col * 8))[1];
        s_p4[2*col]   = make_float4(-2.f*u0.x, -2.f*u0.y, -2.f*u0.z, -2.f*u0.w);
        s_p4[2*col+1] = make_float4(-2.f*u1.x, -2.f*u1.y, -2.f*u1.z, -2.f*u1.w);
        s_y2[col] = u0.x*u0.x + u0.y*u0.y + u0.z*u0.z + u0.w*u0.w
                  + u1.x*u1.x + u1.y*u1.y + u1.z*u1.z + u1.w*u1.w;
    }
    #pragma unroll
    for (int off = 32; off > 0; off >>= 1) msep += __shfl_down(msep, off, 64);
    if (l == 0) s_red[w_] = msep;
    __syncthreads();                      // the ONLY block-wide barrier
    if (tid == 0) ws[blk] = s_red[0] + s_red[1] + s_red[2] + s_red[3];

    unsigned long long* rings = (unsigned long long*)(ws + 320);
    unsigned long long* pub = rings + (size_t)(q * 64 + b) * RING;       // w_==3,q<3
    unsigned long long* con = rings + (size_t)((q - 1) * 64 + b) * RING; // w_==0,q>0
    const int kb_pub   = 256 * q + 192;
    const int kb_con   = 256 * q - 64;
    const int kmax_con = kb_con + 1086;

    const float c1 = 7.213475204444817f;     // log2(e)/gamma
    const float c2 = 0.13862943611198906f;   // gamma*ln(2)
    const int amin = g << 2;                 // first abs window = 4g
    const int amax = amin + 67;
    const int prodmax = amin + 63;           // producer wave's amax = 4(g-1)+67

    float r1 = FINF, r2 = FINF;
    unsigned long long pe1 = 0, pe2 = 0;
    int ppf = 0;
    float hpf1 = 0.f, hpf2 = 0.f;
    int hpff = 0;
    float hv, hvd;

    // stage halo hv (diag k0-1) / hvd (diag k0-2), row gbase-1
    auto stage_halo = [&](int a, int k0, int u) {
        if (w_ == 0) {
            if (q == 0) {
                hv  = FINF;
                hvd = (u == 0 && l == 0) ? 0.0f : FINF;
            } else {
                const int kk1 = k0 - 1 + l, kk2 = k0 - 2 + l;
                const int id1 = min(kk1 - kb_con, RING - 1);
                const int id2 = min(kk2 - kb_con, RING - 1);
                const bool n1 = (l < 16) && (kk1 <= kmax_con);
                const bool n2 = (l < 16) && (kk2 <= kmax_con);
                unsigned long long e1, e2;
                if (ppf) { e1 = pe1; e2 = pe2; ppf = 0; }
                else {
                    e1 = __hip_atomic_load(con + id1, __ATOMIC_RELAXED,
                                           __HIP_MEMORY_SCOPE_AGENT);
                    e2 = __hip_atomic_load(con + id2, __ATOMIC_RELAXED,
                                           __HIP_MEMORY_SCOPE_AGENT);
                }
                while (!__all(((!n1) | ((int)(e1 >> 32) == kk1)) &
                              ((!n2) | ((int)(e2 >> 32) == kk2)))) {
                    e1 = __hip_atomic_load(con + id1, __ATOMIC_RELAXED,
                                           __HIP_MEMORY_SCOPE_AGENT);
                    e2 = __hip_atomic_load(con + id2, __ATOMIC_RELAXED,
                                           __HIP_MEMORY_SCOPE_AGENT);
                }
                hv  = n1 ? __uint_as_float((unsigned)e1) : FINF;
                hvd = n2 ? __uint_as_float((unsigned)e2) : FINF;
            }
        } else {
            if (hpff) { hv = hpf1; hvd = hpf2; hpff = 0; }
            else {
                const int need = (a < prodmax) ? a : prodmax;
                int pv;
                do {
                    pv = __hip_atomic_load(&s_prog[w_ - 1], __ATOMIC_ACQUIRE,
                                           __HIP_MEMORY_SCOPE_WORKGROUP);
                } while (pv < need);
                const int bi = (u << 4) + 63 + l;     // k0-1+l in producer row
                hv  = s_row[w_ - 1][min(bi,     1087)];
                hvd = s_row[w_ - 1][min(bi - 1, 1087)];
            }
        }
    };

// ---- D: distance for one diag, direct per-lane LDS loads ----
// unclamped fast path (interior: j guaranteed in [1,1023])
#define DFAST(i, DST) do {                                                  \
        const float4 va_ = pA[2*(i)];                                       \
        const float4 vb_ = pA[2*(i)+1];                                     \
        const float  yv_ = pY[(i)];                                         \
        float ac_ = x2 + yv_, ac2_ = 0.f;                                   \
        ac_  = fmaf(pa.x, va_.x, ac_ );  ac2_ = fmaf(pa.y, va_.y, ac2_);    \
        ac_  = fmaf(pa.z, va_.z, ac_ );  ac2_ = fmaf(pa.w, va_.w, ac2_);    \
        ac_  = fmaf(pb.x, vb_.x, ac_ );  ac2_ = fmaf(pb.y, vb_.y, ac2_);    \
        ac_  = fmaf(pb.z, vb_.z, ac_ );  ac2_ = fmaf(pb.w, vb_.w, ac2_);    \
        DST = ac_ + ac2_;                                                   \
    } while (0)

// clamped path (edge windows)
#define DCLAMP(JB, i, DST) do {                                             \
        int jc_ = (JB) + (i);                                               \
        jc_ = jc_ < 0 ? 0 : (jc_ > (TT-1) ? (TT-1) : jc_);                  \
        const float4 va_ = s_p4[2*jc_];                                     \
        const float4 vb_ = s_p4[2*jc_+1];                                   \
        const float  yv_ = s_y2[jc_];                                       \
        float ac_ = x2 + yv_, ac2_ = 0.f;                                   \
        ac_  = fmaf(pa.x, va_.x, ac_ );  ac2_ = fmaf(pa.y, va_.y, ac2_);    \
        ac_  = fmaf(pa.z, va_.z, ac_ );  ac2_ = fmaf(pa.w, va_.w, ac2_);    \
        ac_  = fmaf(pb.x, vb_.x, ac_ );  ac2_ = fmaf(pb.y, vb_.y, ac2_);    \
        ac_  = fmaf(pb.z, vb_.z, ac_ );  ac2_ = fmaf(pb.w, vb_.w, ac2_);    \
        DST = ac_ + ac2_;                                                   \
    } while (0)

// ---- R: one softmin recurrence step.  MASKED is a literal 0/1. ----
#define RSTEP(i, DIN, RH, MASKED) do {                                      \
        const float up_   = shflup1(hv,  r1);                               \
        const float dgv_  = shflup1(hvd, r2);                               \
        const float left_ = r1;                                             \
        hv = rotdn1(hv); hvd = rotdn1(hvd);                                 \
        float m_, M_;                                                       \
        asm("v_min3_f32 %0, %1, %2, %3"                                     \
            : "=v"(m_) : "v"(up_), "v"(left_), "v"(dgv_));                  \
        asm("v_max3_f32 %0, %1, %2, %3"                                     \
            : "=v"(M_) : "v"(up_), "v"(left_), "v"(dgv_));                  \
        const float md_ = __builtin_amdgcn_fmed3f(up_, left_, dgv_);        \
        const float mc_ = m_ * c1;                                          \
        const float ea_ = __builtin_amdgcn_exp2f(fmaf(md_, -c1, mc_));      \
        const float eb_ = __builtin_amdgcn_exp2f(fmaf(M_,  -c1, mc_));      \
        const float lg_ = __builtin_amdgcn_logf(1.0f + (ea_ + eb_));        \
        float rn_ = (DIN) + fmaf(-c2, lg_, m_);                             \
        if (MASKED)                                                         \
            rn_ = ((unsigned)(jb0 + (i)) < (unsigned)TT) ? rn_ : FINF;      \
        r2 = r1; r1 = rn_; RH = rn_;                                        \
    } while (0)

    // D for window 0 (prologue, clamped)
    float Dc0,Dc1,Dc2,Dc3,Dc4,Dc5,Dc6,Dc7;
    float Dc8,Dc9,Dc10,Dc11,Dc12,Dc13,Dc14,Dc15;
    {
        const int jb = -l;
        DCLAMP(jb, 0,Dc0 ); DCLAMP(jb, 1,Dc1 ); DCLAMP(jb, 2,Dc2 );
        DCLAMP(jb, 3,Dc3 ); DCLAMP(jb, 4,Dc4 ); DCLAMP(jb, 5,Dc5 );
        DCLAMP(jb, 6,Dc6 ); DCLAMP(jb, 7,Dc7 ); DCLAMP(jb, 8,Dc8 );
        DCLAMP(jb, 9,Dc9 ); DCLAMP(jb,10,Dc10); DCLAMP(jb,11,Dc11);
        DCLAMP(jb,12,Dc12); DCLAMP(jb,13,Dc13); DCLAMP(jb,14,Dc14);
        DCLAMP(jb,15,Dc15);
    }
    float rh14_last = FINF;

    for (int u = 0; u <= 67; ++u) {
        const int a  = amin + u;
        const int k0 = a << 4;
        const int jb0 = (u << 4) - l;        // col index of diag k0 at this lane
        const int jb1 = jb0 + 16;            // same for window u+1

        stage_halo(a, k0, u);

        float E0,E1,E2,E3,E4,E5,E6,E7,E8,E9,E10,E11,E12,E13,E14,E15;
        float rh0,rh1,rh2,rh3,rh4,rh5,rh6,rh7;
        float rh8,rh9,rh10,rh11,rh12,rh13,rh14,rh15;

        if (u >= 4 && u <= 62) {
            // hot fused path: R(u) interleaved with D(u+1), both unguarded
            const float4* pA = &s_p4[2*jb1];
            const float*  pY = &s_y2[jb1];
            RSTEP( 0,Dc0 ,rh0 ,0); DFAST( 0,E0 );
            RSTEP( 1,Dc1 ,rh1 ,0); DFAST( 1,E1 );
            RSTEP( 2,Dc2 ,rh2 ,0); DFAST( 2,E2 );
            RSTEP( 3,Dc3 ,rh3 ,0); DFAST( 3,E3 );
            RSTEP( 4,Dc4 ,rh4 ,0); DFAST( 4,E4 );
            RSTEP( 5,Dc5 ,rh5 ,0); DFAST( 5,E5 );
            RSTEP( 6,Dc6 ,rh6 ,0); DFAST( 6,E6 );
            RSTEP( 7,Dc7 ,rh7 ,0); DFAST( 7,E7 );
            RSTEP( 8,Dc8 ,rh8 ,0); DFAST( 8,E8 );
            RSTEP( 9,Dc9 ,rh9 ,0); DFAST( 9,E9 );
            RSTEP(10,Dc10,rh10,0); DFAST(10,E10);
            RSTEP(11,Dc11,rh11,0); DFAST(11,E11);
            RSTEP(12,Dc12,rh12,0); DFAST(12,E12);
            RSTEP(13,Dc13,rh13,0); DFAST(13,E13);
            RSTEP(14,Dc14,rh14,0); DFAST(14,E14);
            RSTEP(15,Dc15,rh15,0); DFAST(15,E15);
        } else {
            // edge windows: masked R; clamped D for u+1 (skip at u=67)
            RSTEP( 0,Dc0 ,rh0 ,1); RSTEP( 1,Dc1 ,rh1 ,1);
            RSTEP( 2,Dc2 ,rh2 ,1); RSTEP( 3,Dc3 ,rh3 ,1);
            RSTEP( 4,Dc4 ,rh4 ,1); RSTEP( 5,Dc5 ,rh5 ,1);
            RSTEP( 6,Dc6 ,rh6 ,1); RSTEP( 7,Dc7 ,rh7 ,1);
            RSTEP( 8,Dc8 ,rh8 ,1); RSTEP( 9,Dc9 ,rh9 ,1);
            RSTEP(10,Dc10,rh10,1); RSTEP(11,Dc11,rh11,1);
            RSTEP(12,Dc12,rh12,1); RSTEP(13,Dc13,rh13,1);
            RSTEP(14,Dc14,rh14,1); RSTEP(15,Dc15,rh15,1);
            if (u < 67) {
                DCLAMP(jb1, 0,E0 ); DCLAMP(jb1, 1,E1 ); DCLAMP(jb1, 2,E2 );
                DCLAMP(jb1, 3,E3 ); DCLAMP(jb1, 4,E4 ); DCLAMP(jb1, 5,E5 );
                DCLAMP(jb1, 6,E6 ); DCLAMP(jb1, 7,E7 ); DCLAMP(jb1, 8,E8 );
                DCLAMP(jb1, 9,E9 ); DCLAMP(jb1,10,E10); DCLAMP(jb1,11,E11);
                DCLAMP(jb1,12,E12); DCLAMP(jb1,13,E13); DCLAMP(jb1,14,E14);
                DCLAMP(jb1,15,E15);
            } else {
                E0=E1=E2=E3=E4=E5=E6=E7=0.f;
                E8=E9=E10=E11=E12=E13=E14=E15=0.f;
                rh14_last = rh14;
            }
        }

        // bottom-row store (packed; masked FINF entries are correct values)
        if (l == 63) {
            float4* dst = (float4*)&s_row[w_][u << 4];
            dst[0] = make_float4(rh0,  rh1,  rh2,  rh3);
            dst[1] = make_float4(rh4,  rh5,  rh6,  rh7);
            dst[2] = make_float4(rh8,  rh9,  rh10, rh11);
            dst[3] = make_float4(rh12, rh13, rh14, rh15);
        }
        // rotate D buffers
        Dc0=E0;  Dc1=E1;  Dc2=E2;  Dc3=E3;  Dc4=E4;  Dc5=E5;  Dc6=E6;  Dc7=E7;
        Dc8=E8;  Dc9=E9;  Dc10=E10;Dc11=E11;Dc12=E12;Dc13=E13;Dc14=E14;Dc15=E15;

        // ---- mark window complete for intra-block consumer ----
        if (w_ < 3 && l == 0) {
            __hip_atomic_store(&s_prog[w_], a, __ATOMIC_RELEASE,
                               __HIP_MEMORY_SCOPE_WORKGROUP);
        }
        // ---- producer: publish window as self-validating u64 entries ----
        if (w_ == 3 && q < 3) {
            if (l < 16) {
                const int kk = k0 + l;
                const unsigned long long ev =
                    ((unsigned long long)(unsigned)kk << 32) |
                    (unsigned long long)__float_as_uint(s_row[3][(u << 4) + l]);
                __hip_atomic_store(pub + (kk - kb_pub), ev,
                                   __ATOMIC_RELAXED, __HIP_MEMORY_SCOPE_AGENT);
            }
        }
        // ---- cross-block consumer: prefetch next window's halo entries ----
        if (w_ == 0 && q > 0 && a < amax) {
            const int k0n = k0 + 16;
            const int kk1 = k0n - 1 + l, kk2 = k0n - 2 + l;
            pe1 = __hip_atomic_load(con + min(kk1 - kb_con, RING - 1),
                                    __ATOMIC_RELAXED, __HIP_MEMORY_SCOPE_AGENT);
            pe2 = __hip_atomic_load(con + min(kk2 - kb_con, RING - 1),
                                    __ATOMIC_RELAXED, __HIP_MEMORY_SCOPE_AGENT);
            ppf = 1;
        }
        // ---- intra-block consumer: prefetch next window's halo if ready ----
        if (w_ != 0 && a < amax) {
            const int neednx = ((a + 1) < prodmax) ? (a + 1) : prodmax;
            const int pv = __hip_atomic_load(&s_prog[w_ - 1], __ATOMIC_ACQUIRE,
                                             __HIP_MEMORY_SCOPE_WORKGROUP);
            if (pv >= neednx) {
                const int bi = ((u + 1) << 4) + 63 + l;
                hpf1 = s_row[w_ - 1][min(bi,     1087)];
                hpf2 = s_row[w_ - 1][min(bi - 1, 1087)];
                hpff = 1;
            }
        }
    }
    if (q == 3 && tid == 255) ws[256 + b] = rh14_last;   // r_{2T-2}(T-1)
#undef DFAST
#undef DCLAMP
#undef RSTEP
}

__global__ __launch_bounds__(256) void finalize2_kernel(
    const float* __restrict__ ws, float* __restrict__ out)
{
    __shared__ float sm[4], ss[4];
    const int tid = threadIdx.x, l = tid & 63, w = tid >> 6;
    float m  = ws[tid];
    float sd = (tid < 64) ? ws[256 + tid] : 0.f;
    #pragma unroll
    for (int off = 32; off > 0; off >>= 1) {
        m  += __shfl_down(m,  off, 64);
        sd += __shfl_down(sd, off, 64);
    }
    if (l == 0) { sm[w] = m; ss[w] = sd; }
    __syncthreads();
    if (tid == 0) {
        float M = sm[0] + sm[1] + sm[2] + sm[3];
        float S = ss[0] + ss[1] + ss[2] + ss[3];
        out[0] = ALPHA_ * (M / 524288.0f) + (1.0f - ALPHA_) * (S / 64.0f);
    }
}

extern "C" void kernel_launch(void* const* d_in, const int* in_sizes, int n_in,
                              void* d_out, int out_size, void* d_ws, size_t ws_size,
                              hipStream_t stream) {
    const float* pred   = (const float*)d_in[0];
    const float* target = (const float*)d_in[1];
    float* ws  = (float*)d_ws;
    float* out = (float*)d_out;

    sdtw_band_kernel<<<256, 256, 0, stream>>>(pred, target, ws);
    finalize2_kernel<<<1, 256, 0, stream>>>(ws, out);
}